// Round 2
// baseline (137.014 us; speedup 1.0000x reference)
//
#include <hip/hip_runtime.h>
#include <math.h>

#define NB   4      // n
#define C    128    // channels
#define S    31     // frames
#define HW   704    // h*w = 32*22
#define T    30     // s-1
#define NS   120    // n*(s-1)
#define K    16     // top_k
#define NFR  124    // NB*S frames
#define NG   21824  // total float4 groups = NB*S*HW/4

// ---------------------------------------------------------------------------
// Kernel 1: 1x1 conv (C->1), float4-vectorized, WITH FUSED top/bottom-16
// select (last-writer-block pattern — removes the standalone select dispatch
// and hides its ~2us under conv's memory phase).
//
// Conv part (unchanged): each lane owns one float4 (4 consecutive pixels);
// wave = 256 contiguous pixels; 4 waves/block = 4 channel-groups of 32, LDS
// combine. 341 blocks x 4 waves = 1364 waves. 16B/lane loads -> BW floor
// ~7.2 us.
//
// Select fusion: B-frame fr is written by blocks [(fr*176)>>6,
// (fr*176+175)>>6] (3 or 4 writers). After writing, each writer releases
// (__threadfence: device-scope, covers cross-XCD L2 per G16) and
// atomicAdd's cnt[fr]. Counters live in poisoned ws: the harness fill is a
// uniform <=16B pattern, so a spare slot at the same 16B phase supplies the
// poison base P; last-writer test is old == P + nw - 1 (wrap-safe unsigned).
// The last writer's wave 0 runs the 16-round max/min extraction for that
// pair, overlapping the remaining conv blocks' loads.
// ---------------------------------------------------------------------------
__global__ __launch_bounds__(256) void conv_select_kernel(
    const float* __restrict__ x,
    const float* __restrict__ w1, const float* __restrict__ b1p,
    const float* __restrict__ w2, const float* __restrict__ b2p,
    float* __restrict__ A, float* __restrict__ B,
    float* __restrict__ btop, float* __restrict__ bbot,
    unsigned* __restrict__ cnt) {
  const int tid  = threadIdx.x;
  const int lane = tid & 63;
  const int cg   = tid >> 6;                 // wave-uniform channel group
  const int g    = blockIdx.x * 64 + lane;   // float4 index, 0..21823
  const int fr   = g / 176;                  // (n, sf), 176 float4s per frame
  const int f4   = g % 176;
  const int sf   = fr % S;
  const int n    = fr / S;

  const float4* xp =
      (const float4*)(x + (((size_t)(n * C + cg * 32) * S + sf) * HW)) + f4;
  float4 a1 = make_float4(0.f, 0.f, 0.f, 0.f);
  float4 a2 = make_float4(0.f, 0.f, 0.f, 0.f);
#pragma unroll
  for (int c = 0; c < 32; ++c) {
    float4 xv = xp[(size_t)c * (S * HW / 4)];
    const float wa = w1[cg * 32 + c];        // wave-uniform -> s_load
    const float wb = w2[cg * 32 + c];
    a1.x = fmaf(xv.x, wa, a1.x); a1.y = fmaf(xv.y, wa, a1.y);
    a1.z = fmaf(xv.z, wa, a1.z); a1.w = fmaf(xv.w, wa, a1.w);
    a2.x = fmaf(xv.x, wb, a2.x); a2.y = fmaf(xv.y, wb, a2.y);
    a2.z = fmaf(xv.z, wb, a2.z); a2.w = fmaf(xv.w, wb, a2.w);
  }
  __shared__ float4 s1[4][64];
  __shared__ float4 s2[4][64];
  __shared__ int selpair[2];
  s1[cg][lane] = a1;
  s2[cg][lane] = a2;
  __syncthreads();
  if (tid < 64) {
    float4 r1 = s1[0][tid], r2 = s2[0][tid];
#pragma unroll
    for (int u = 1; u < 4; ++u) {
      float4 t1 = s1[u][tid], t2 = s2[u][tid];
      r1.x += t1.x; r1.y += t1.y; r1.z += t1.z; r1.w += t1.w;
      r2.x += t2.x; r2.y += t2.y; r2.z += t2.z; r2.w += t2.w;
    }
    const float bb1 = b1p[0], bb2 = b2p[0];
    r1.x += bb1; r1.y += bb1; r1.z += bb1; r1.w += bb1;
    r2.x += bb2; r2.y += bb2; r2.z += bb2; r2.w += bb2;
    if (sf < T)
      ((float4*)(A + (size_t)(n * T + sf) * HW))[f4] = r1;
    if (sf >= 1)
      ((float4*)(B + (size_t)(n * T + sf - 1) * HW))[f4] = r2;
    __threadfence();   // release this wave's B writes device-wide (wbl2)
  }
  __syncthreads();

  if (tid == 0) {
    const int g0  = blockIdx.x * 64;
    const int fr0 = g0 / 176;
    const int fr1 = (g0 + 63) / 176;   // fr1 - fr0 <= 1
    int nsel = 0;
    for (int f = fr0; f <= fr1; ++f) {
      const int fsf = f % S;
      if (fsf >= 1) {
        const int first = (f * 176) >> 6;
        const int last  = (f * 176 + 175) >> 6;
        const unsigned nw = (unsigned)(last - first + 1);
        // poison base: spare slot at identical 16B phase (uniform fill)
        const unsigned base = cnt[(NFR + f) * 4];
        const unsigned old  = atomicAdd(&cnt[f * 4], 1u);
        if (old == base + nw - 1u)
          selpair[nsel++] = (f / S) * T + fsf - 1;   // pair index
      }
    }
    while (nsel < 2) selpair[nsel++] = -1;
  }
  __syncthreads();

  // wave 0 performs the 16-round top/bottom extraction for won pairs
  if (tid < 64) {
#pragma unroll 1
    for (int q = 0; q < 2; ++q) {
      const int i = selpair[q];
      if (i < 0) continue;
      __threadfence();                 // acquire: see other blocks' B writes
      const float* bi = B + i * HW;
      float vt[11], vb[11];
#pragma unroll
      for (int j = 0; j < 11; ++j) {
        const float v = bi[j * 64 + tid];
        vt[j] = v;
        vb[j] = v;
      }
#pragma unroll 1
      for (int r = 0; r < K; ++r) {
        float lmT = vt[0], lmB = vb[0];
#pragma unroll
        for (int j = 1; j < 11; ++j) {
          lmT = fmaxf(lmT, vt[j]);
          lmB = fminf(lmB, vb[j]);
        }
        float gT = lmT, gB = lmB;
#pragma unroll
        for (int off = 1; off < 64; off <<= 1) {
          gT = fmaxf(gT, __shfl_xor(gT, off, 64));
          gB = fminf(gB, __shfl_xor(gB, off, 64));
        }
        const unsigned long long mT = __ballot(lmT == gT);
        const unsigned long long mB = __ballot(lmB == gB);
        if (tid == (int)(__ffsll(mT) - 1)) {
          bool done = false;
#pragma unroll
          for (int j = 0; j < 11; ++j) {
            const bool hit = (!done) && (vt[j] == gT);
            vt[j] = hit ? -INFINITY : vt[j];
            done  = done || hit;
          }
        }
        if (tid == (int)(__ffsll(mB) - 1)) {
          bool done = false;
#pragma unroll
          for (int j = 0; j < 11; ++j) {
            const bool hit = (!done) && (vb[j] == gB);
            vb[j] = hit ? INFINITY : vb[j];
            done  = done || hit;
          }
        }
        if (tid == 0) {
          btop[i * K + r] = gT;  // r-th largest  -> descending
          bbot[i * K + r] = gB;  // r-th smallest -> ascending
        }
      }
    }
  }
}

// ---------------------------------------------------------------------------
// Kernel 2: one wave per FOUR rows of the same frame pair (r, r+176, r+352,
// r+528). 21120 waves, 5280 blocks (~20 waves/CU TLP). Each b element
// loaded once feeds 4 exps (L2 re-read quartered to ~60 MB, 4-way ILP on
// the exp chain, quarter the butterfly work). Lane l covers q = j*64+l
// (coalesced). ln2 folded into the fma -> raw v_exp_f32. m = exact row max
// of a*b so every exponent <= 0; a==0 -> uniform 1/704 automatically.
// Output raw-reshape: row r -> (j_out=r/44, p_out=(r%44)*16), 16 contiguous
// floats per row.
// ---------------------------------------------------------------------------
__global__ __launch_bounds__(256) void softmax_topk_kernel(
    const float* __restrict__ A, const float* __restrict__ B,
    const float* __restrict__ btop, const float* __restrict__ bbot,
    float* __restrict__ out) {
  const int lane = threadIdx.x & 63;
  const int wid  = blockIdx.x * 4 + (threadIdx.x >> 6);  // 0..21119
  const int i    = wid / 176;                            // frame pair
  const int rb   = wid % 176;                            // base row

  const float st0 = btop[i * K];
  const float sb0 = bbot[i * K];
  const float L2E = 1.4426950408889634f;
  float av[4], a2[4], nm[4], part[4];
#pragma unroll
  for (int u = 0; u < 4; ++u) {
    av[u]   = A[i * HW + rb + u * 176];
    a2[u]   = av[u] * L2E;
    nm[u]   = -((av[u] >= 0.f) ? av[u] * st0 : av[u] * sb0) * L2E;
    part[u] = 0.f;
  }

  const float* __restrict__ bi = B + i * HW;
#pragma unroll
  for (int j = 0; j < 11; ++j) {
    const float bv = bi[j * 64 + lane];
#pragma unroll
    for (int u = 0; u < 4; ++u)
      part[u] += __builtin_amdgcn_exp2f(fmaf(a2[u], bv, nm[u]));
  }
#pragma unroll
  for (int off = 1; off < 64; off <<= 1) {
#pragma unroll
    for (int u = 0; u < 4; ++u)
      part[u] += __shfl_xor(part[u], off, 64);
  }

  if (lane < K) {
    const int n  = i / T;
    const int t  = i % T;
    float* obase = out + (((size_t)n * K) * T + t) * HW;
    const float tv = btop[i * K + lane];
    const float bv = bbot[i * K + lane];
#pragma unroll
    for (int u = 0; u < 4; ++u) {
      const int r = rb + u * 176;
      const float sel = (av[u] >= 0.f) ? tv : bv;
      const float val = __builtin_amdgcn_exp2f(fmaf(a2[u], sel, nm[u])) / part[u];
      obase[(size_t)(r / 44) * (T * HW) + (r % 44) * K + lane] = val;
    }
  }
}

extern "C" void kernel_launch(void* const* d_in, const int* in_sizes, int n_in,
                              void* d_out, int out_size, void* d_ws, size_t ws_size,
                              hipStream_t stream) {
  (void)in_sizes; (void)n_in; (void)out_size; (void)ws_size;
  const float* x  = (const float*)d_in[0];
  const float* w1 = (const float*)d_in[1];
  const float* b1 = (const float*)d_in[2];
  const float* w2 = (const float*)d_in[3];
  const float* b2 = (const float*)d_in[4];
  // d_in[5] is top_k (=16), hardcoded as K.
  float* out = (float*)d_out;

  float* A    = (float*)d_ws;            // NS*HW
  float* B    = A + NS * HW;             // NS*HW
  float* btop = B + NS * HW;             // NS*K
  float* bbot = btop + NS * K;           // NS*K
  // counters: 16B-strided uints in poisoned ws; spares at same 16B phase
  // supply the (uniform) poison base. 2*NFR*16B = 3968 B past bbot.
  unsigned* cnt = (unsigned*)(bbot + NS * K);

  conv_select_kernel<<<341, 256, 0, stream>>>(x, w1, b1, w2, b2,
                                              A, B, btop, bbot, cnt);
  softmax_topk_kernel<<<5280, 256, 0, stream>>>(A, B, btop, bbot, out);
}

// Round 3
// 114.865 us; speedup vs baseline: 1.1928x; 1.1928x over previous
//
#include <hip/hip_runtime.h>
#include <math.h>

#define NB   4      // n
#define C    128    // channels
#define S    31     // frames
#define HW   704    // h*w = 32*22
#define T    30     // s-1
#define NS   120    // n*(s-1)
#define K    16     // top_k
#define NFR  124    // NB*S frames

// ---------------------------------------------------------------------------
// Kernel 1: 1x1 conv (C->1) + BLOCK-LOCAL fused top/bottom-16 select.
// One block per frame (124 blocks x 768 threads = 12 waves). 4 channel-
// groups x 3 waves; within a group, 176 of 192 lanes own one float4 (4
// consecutive pixels) and march 32 channels (stride S*HW). LDS combine of
// the 4 partials, then the block holds the COMPLETE 704-value B row in LDS
// -> wave 0 runs the 16-round max/min extraction with no fences, no
// atomics, no cross-block traffic (round-2's device-fence fusion cost
// 42 us in L2 writeback/invalidate; this is the block-local redesign).
// Same total x traffic (each element read once, dwordx4), ~1488 waves.
// ---------------------------------------------------------------------------
__global__ __launch_bounds__(768) void conv_select_kernel(
    const float* __restrict__ x,
    const float* __restrict__ w1, const float* __restrict__ b1p,
    const float* __restrict__ w2, const float* __restrict__ b2p,
    float* __restrict__ A, float* __restrict__ B,
    float* __restrict__ btop, float* __restrict__ bbot) {
  const int tid = threadIdx.x;
  // wave id via readfirstlane -> cg lands in an SGPR (weight reads = s_load)
  const int wv    = __builtin_amdgcn_readfirstlane(tid) >> 6;  // 0..11
  const int cg    = wv / 3;                                    // 0..3
  const int local = tid - cg * 192;                            // 0..191
  const bool act  = local < 176;
  const int f4    = act ? local : 175;     // clamp: idle lanes load a dup
  const int fr    = blockIdx.x;            // frame 0..123
  const int sf    = fr % S;
  const int n     = fr / S;

  const float4* xp =
      (const float4*)(x + (((size_t)(n * C + cg * 32) * S + sf) * HW)) + f4;
  float4 a1 = make_float4(0.f, 0.f, 0.f, 0.f);
  float4 a2 = make_float4(0.f, 0.f, 0.f, 0.f);
#pragma unroll
  for (int c = 0; c < 32; ++c) {
    float4 xv = xp[(size_t)c * (S * HW / 4)];
    const float wa = w1[cg * 32 + c];      // SGPR index -> s_load
    const float wb = w2[cg * 32 + c];
    a1.x = fmaf(xv.x, wa, a1.x); a1.y = fmaf(xv.y, wa, a1.y);
    a1.z = fmaf(xv.z, wa, a1.z); a1.w = fmaf(xv.w, wa, a1.w);
    a2.x = fmaf(xv.x, wb, a2.x); a2.y = fmaf(xv.y, wb, a2.y);
    a2.z = fmaf(xv.z, wb, a2.z); a2.w = fmaf(xv.w, wb, a2.w);
  }

  __shared__ float4 s1[4][176];
  __shared__ float4 s2[4][176];
  if (act) {
    s1[cg][f4] = a1;
    s2[cg][f4] = a2;
  }
  __syncthreads();

  if (tid < 176) {
    float4 r1 = s1[0][tid], r2 = s2[0][tid];
#pragma unroll
    for (int u = 1; u < 4; ++u) {
      float4 t1 = s1[u][tid], t2 = s2[u][tid];
      r1.x += t1.x; r1.y += t1.y; r1.z += t1.z; r1.w += t1.w;
      r2.x += t2.x; r2.y += t2.y; r2.z += t2.z; r2.w += t2.w;
    }
    const float bb1 = b1p[0], bb2 = b2p[0];
    r1.x += bb1; r1.y += bb1; r1.z += bb1; r1.w += bb1;
    r2.x += bb2; r2.y += bb2; r2.z += bb2; r2.w += bb2;
    if (sf < T)
      ((float4*)(A + (size_t)(n * T + sf) * HW))[tid] = r1;
    if (sf >= 1)
      ((float4*)(B + (size_t)(n * T + sf - 1) * HW))[tid] = r2;
    // park the final (biased) B row in s2[0][*]: column tid is owned by
    // this thread only -> no race with the s2 reads above
    s2[0][tid] = r2;
  }
  __syncthreads();

  // wave 0: 16-round max/min extraction of the B row, straight from LDS.
  // 704 = 11*64 values, 11/lane in registers, static indices only.
  if (tid < 64 && sf >= 1) {
    const int i = n * T + sf - 1;          // pair index
    const float* bs = (const float*)&s2[0][0];
    float vt[11], vb[11];
#pragma unroll
    for (int j = 0; j < 11; ++j) {
      const float v = bs[j * 64 + tid];    // stride-64 floats: conflict-free
      vt[j] = v;
      vb[j] = v;
    }
#pragma unroll 1
    for (int r = 0; r < K; ++r) {
      float lmT = vt[0], lmB = vb[0];
#pragma unroll
      for (int j = 1; j < 11; ++j) {
        lmT = fmaxf(lmT, vt[j]);
        lmB = fminf(lmB, vb[j]);
      }
      float gT = lmT, gB = lmB;
#pragma unroll
      for (int off = 1; off < 64; off <<= 1) {
        gT = fmaxf(gT, __shfl_xor(gT, off, 64));
        gB = fminf(gB, __shfl_xor(gB, off, 64));
      }
      const unsigned long long mT = __ballot(lmT == gT);
      const unsigned long long mB = __ballot(lmB == gB);
      if (tid == (int)(__ffsll(mT) - 1)) {
        bool done = false;
#pragma unroll
        for (int j = 0; j < 11; ++j) {
          const bool hit = (!done) && (vt[j] == gT);
          vt[j] = hit ? -INFINITY : vt[j];
          done  = done || hit;
        }
      }
      if (tid == (int)(__ffsll(mB) - 1)) {
        bool done = false;
#pragma unroll
        for (int j = 0; j < 11; ++j) {
          const bool hit = (!done) && (vb[j] == gB);
          vb[j] = hit ? INFINITY : vb[j];
          done  = done || hit;
        }
      }
      if (tid == 0) {
        btop[i * K + r] = gT;  // r-th largest  -> descending
        bbot[i * K + r] = gB;  // r-th smallest -> ascending
      }
    }
  }
}

// ---------------------------------------------------------------------------
// Kernel 2: one wave per FOUR rows of the same frame pair (r, r+176, r+352,
// r+528). 21120 waves, 5280 blocks (~20 waves/CU TLP). Each b element
// loaded once feeds 4 exps (L2 re-read quartered to ~60 MB, 4-way ILP on
// the exp chain, quarter the butterfly work). Lane l covers q = j*64+l
// (coalesced). ln2 folded into the fma -> raw v_exp_f32. m = exact row max
// of a*b so every exponent <= 0; a==0 -> uniform 1/704 automatically.
// Output raw-reshape: row r -> (j_out=r/44, p_out=(r%44)*16), 16 contiguous
// floats per row.
// ---------------------------------------------------------------------------
__global__ __launch_bounds__(256) void softmax_topk_kernel(
    const float* __restrict__ A, const float* __restrict__ B,
    const float* __restrict__ btop, const float* __restrict__ bbot,
    float* __restrict__ out) {
  const int lane = threadIdx.x & 63;
  const int wid  = blockIdx.x * 4 + (threadIdx.x >> 6);  // 0..21119
  const int i    = wid / 176;                            // frame pair
  const int rb   = wid % 176;                            // base row

  const float st0 = btop[i * K];
  const float sb0 = bbot[i * K];
  const float L2E = 1.4426950408889634f;
  float av[4], a2[4], nm[4], part[4];
#pragma unroll
  for (int u = 0; u < 4; ++u) {
    av[u]   = A[i * HW + rb + u * 176];
    a2[u]   = av[u] * L2E;
    nm[u]   = -((av[u] >= 0.f) ? av[u] * st0 : av[u] * sb0) * L2E;
    part[u] = 0.f;
  }

  const float* __restrict__ bi = B + i * HW;
#pragma unroll
  for (int j = 0; j < 11; ++j) {
    const float bv = bi[j * 64 + lane];
#pragma unroll
    for (int u = 0; u < 4; ++u)
      part[u] += __builtin_amdgcn_exp2f(fmaf(a2[u], bv, nm[u]));
  }
#pragma unroll
  for (int off = 1; off < 64; off <<= 1) {
#pragma unroll
    for (int u = 0; u < 4; ++u)
      part[u] += __shfl_xor(part[u], off, 64);
  }

  if (lane < K) {
    const int n  = i / T;
    const int t  = i % T;
    float* obase = out + (((size_t)n * K) * T + t) * HW;
    const float tv = btop[i * K + lane];
    const float bv = bbot[i * K + lane];
#pragma unroll
    for (int u = 0; u < 4; ++u) {
      const int r = rb + u * 176;
      const float sel = (av[u] >= 0.f) ? tv : bv;
      const float val = __builtin_amdgcn_exp2f(fmaf(a2[u], sel, nm[u])) / part[u];
      obase[(size_t)(r / 44) * (T * HW) + (r % 44) * K + lane] = val;
    }
  }
}

extern "C" void kernel_launch(void* const* d_in, const int* in_sizes, int n_in,
                              void* d_out, int out_size, void* d_ws, size_t ws_size,
                              hipStream_t stream) {
  (void)in_sizes; (void)n_in; (void)out_size; (void)ws_size;
  const float* x  = (const float*)d_in[0];
  const float* w1 = (const float*)d_in[1];
  const float* b1 = (const float*)d_in[2];
  const float* w2 = (const float*)d_in[3];
  const float* b2 = (const float*)d_in[4];
  // d_in[5] is top_k (=16), hardcoded as K.
  float* out = (float*)d_out;

  float* A    = (float*)d_ws;            // NS*HW
  float* B    = A + NS * HW;             // NS*HW
  float* btop = B + NS * HW;             // NS*K
  float* bbot = btop + NS * K;           // NS*K

  conv_select_kernel<<<NFR, 768, 0, stream>>>(x, w1, b1, w2, b2,
                                              A, B, btop, bbot);
  softmax_topk_kernel<<<5280, 256, 0, stream>>>(A, B, btop, bbot, out);
}

// Round 4
// 107.876 us; speedup vs baseline: 1.2701x; 1.0648x over previous
//
#include <hip/hip_runtime.h>
#include <math.h>

#define NB   4      // n
#define C    128    // channels
#define S    31     // frames
#define HW   704    // h*w = 32*22
#define T    30     // s-1
#define NS   120    // n*(s-1)
#define K    16     // top_k
#define NFR  124    // NB*S frames

// ---------------------------------------------------------------------------
// Kernel 1: 1x1 conv (C->1) + BLOCK-LOCAL fused top/bottom-16 select.
// One block per frame (124 blocks x 768 threads = 12 waves). 4 channel-
// groups x 3 waves; within a group, 176 of 192 lanes own one float4 (4
// consecutive pixels) and march 32 channels (stride S*HW). LDS combine of
// the 4 partials, then the block holds the COMPLETE 704-value B row in LDS
// -> wave 0 runs the 16-round max/min extraction with no fences, no
// atomics, no cross-block traffic. (Unchanged from round 3.)
// ---------------------------------------------------------------------------
__global__ __launch_bounds__(768) void conv_select_kernel(
    const float* __restrict__ x,
    const float* __restrict__ w1, const float* __restrict__ b1p,
    const float* __restrict__ w2, const float* __restrict__ b2p,
    float* __restrict__ A, float* __restrict__ B,
    float* __restrict__ btop, float* __restrict__ bbot) {
  const int tid = threadIdx.x;
  // wave id via readfirstlane -> cg lands in an SGPR (weight reads = s_load)
  const int wv    = __builtin_amdgcn_readfirstlane(tid) >> 6;  // 0..11
  const int cg    = wv / 3;                                    // 0..3
  const int local = tid - cg * 192;                            // 0..191
  const bool act  = local < 176;
  const int f4    = act ? local : 175;     // clamp: idle lanes load a dup
  const int fr    = blockIdx.x;            // frame 0..123
  const int sf    = fr % S;
  const int n     = fr / S;

  const float4* xp =
      (const float4*)(x + (((size_t)(n * C + cg * 32) * S + sf) * HW)) + f4;
  float4 a1 = make_float4(0.f, 0.f, 0.f, 0.f);
  float4 a2 = make_float4(0.f, 0.f, 0.f, 0.f);
#pragma unroll
  for (int c = 0; c < 32; ++c) {
    float4 xv = xp[(size_t)c * (S * HW / 4)];
    const float wa = w1[cg * 32 + c];      // SGPR index -> s_load
    const float wb = w2[cg * 32 + c];
    a1.x = fmaf(xv.x, wa, a1.x); a1.y = fmaf(xv.y, wa, a1.y);
    a1.z = fmaf(xv.z, wa, a1.z); a1.w = fmaf(xv.w, wa, a1.w);
    a2.x = fmaf(xv.x, wb, a2.x); a2.y = fmaf(xv.y, wb, a2.y);
    a2.z = fmaf(xv.z, wb, a2.z); a2.w = fmaf(xv.w, wb, a2.w);
  }

  __shared__ float4 s1[4][176];
  __shared__ float4 s2[4][176];
  if (act) {
    s1[cg][f4] = a1;
    s2[cg][f4] = a2;
  }
  __syncthreads();

  if (tid < 176) {
    float4 r1 = s1[0][tid], r2 = s2[0][tid];
#pragma unroll
    for (int u = 1; u < 4; ++u) {
      float4 t1 = s1[u][tid], t2 = s2[u][tid];
      r1.x += t1.x; r1.y += t1.y; r1.z += t1.z; r1.w += t1.w;
      r2.x += t2.x; r2.y += t2.y; r2.z += t2.z; r2.w += t2.w;
    }
    const float bb1 = b1p[0], bb2 = b2p[0];
    r1.x += bb1; r1.y += bb1; r1.z += bb1; r1.w += bb1;
    r2.x += bb2; r2.y += bb2; r2.z += bb2; r2.w += bb2;
    if (sf < T)
      ((float4*)(A + (size_t)(n * T + sf) * HW))[tid] = r1;
    if (sf >= 1)
      ((float4*)(B + (size_t)(n * T + sf - 1) * HW))[tid] = r2;
    // park the final (biased) B row in s2[0][*]: column tid is owned by
    // this thread only -> no race with the s2 reads above
    s2[0][tid] = r2;
  }
  __syncthreads();

  // wave 0: 16-round max/min extraction of the B row, straight from LDS.
  // 704 = 11*64 values, 11/lane in registers, static indices only.
  if (tid < 64 && sf >= 1) {
    const int i = n * T + sf - 1;          // pair index
    const float* bs = (const float*)&s2[0][0];
    float vt[11], vb[11];
#pragma unroll
    for (int j = 0; j < 11; ++j) {
      const float v = bs[j * 64 + tid];    // stride-64 floats: conflict-free
      vt[j] = v;
      vb[j] = v;
    }
#pragma unroll 1
    for (int r = 0; r < K; ++r) {
      float lmT = vt[0], lmB = vb[0];
#pragma unroll
      for (int j = 1; j < 11; ++j) {
        lmT = fmaxf(lmT, vt[j]);
        lmB = fminf(lmB, vb[j]);
      }
      float gT = lmT, gB = lmB;
#pragma unroll
      for (int off = 1; off < 64; off <<= 1) {
        gT = fmaxf(gT, __shfl_xor(gT, off, 64));
        gB = fminf(gB, __shfl_xor(gB, off, 64));
      }
      const unsigned long long mT = __ballot(lmT == gT);
      const unsigned long long mB = __ballot(lmB == gB);
      if (tid == (int)(__ffsll(mT) - 1)) {
        bool done = false;
#pragma unroll
        for (int j = 0; j < 11; ++j) {
          const bool hit = (!done) && (vt[j] == gT);
          vt[j] = hit ? -INFINITY : vt[j];
          done  = done || hit;
        }
      }
      if (tid == (int)(__ffsll(mB) - 1)) {
        bool done = false;
#pragma unroll
        for (int j = 0; j < 11; ++j) {
          const bool hit = (!done) && (vb[j] == gB);
          vb[j] = hit ? INFINITY : vb[j];
          done  = done || hit;
        }
      }
      if (tid == 0) {
        btop[i * K + r] = gT;  // r-th largest  -> descending
        bbot[i * K + r] = gB;  // r-th smallest -> ascending
      }
    }
  }
}

// ---------------------------------------------------------------------------
// Kernel 2 (RESTRUCTURED): lane-serial softmax denominator — NO butterfly.
// Grid = 120 pairs x 11 row-slabs = 1320 blocks x 256 threads (4 waves,
// ~5.2 waves/SIMD, full chip). Block stages its pair's B row (176 float4 =
// 2.8 KB) + btop/bbot into LDS once. Lane r owns output row slab*64+lane;
// the 4 waves q-split 704 columns into 176 each. Inner loop per 4 q:
// 1 broadcast ds_read_b128 (wave-uniform address = conflict-free) +
// 4x(fma, v_exp, add). Denominator combine = LDS partial + 3 adds (replaces
// the 24-shuffle-per-wave butterfly). B global re-read: 59 MB -> 3.7 MB.
// m = exact row max of a*b (via st0/sb0) so every exponent <= 0.
// ---------------------------------------------------------------------------
__global__ __launch_bounds__(256) void softmax_topk_kernel(
    const float* __restrict__ A, const float* __restrict__ B,
    const float* __restrict__ btop, const float* __restrict__ bbot,
    float* __restrict__ out) {
  __shared__ float4 bs4[176];         // pair's full B row
  __shared__ float  partial[4][64];   // per-wave denominator partials
  __shared__ float  seltop[K], selbot[K];
  const int tid  = threadIdx.x;
  const int lane = tid & 63;
  const int w    = tid >> 6;                  // wave 0..3 (q-split)
  const int i    = blockIdx.x / 11;           // frame pair (11 consecutive
  const int slab = blockIdx.x % 11;           //  blocks share B row in L2)
  const int n    = i / T;
  const int tp   = i % T;

  if (tid < 176) bs4[tid] = ((const float4*)(B + i * HW))[tid];
  if (tid >= 176 && tid < 176 + K) {
    seltop[tid - 176] = btop[i * K + (tid - 176)];
    selbot[tid - 176] = bbot[i * K + (tid - 176)];
  }

  const int   r   = slab * 64 + lane;         // this lane's output row
  const float a   = A[i * HW + r];
  const float st0 = btop[i * K];
  const float sb0 = bbot[i * K];
  const float L2E = 1.4426950408889634f;
  const float a2  = a * L2E;
  const float nm  = -((a >= 0.f) ? a * st0 : a * sb0) * L2E;
  __syncthreads();

  // lane-serial denominator over this wave's 176-column span
  float p0 = 0.f, p1 = 0.f, p2 = 0.f, p3 = 0.f;
#pragma unroll 11
  for (int j = 0; j < 44; ++j) {
    const float4 bq = bs4[w * 44 + j];        // broadcast ds_read_b128
    p0 += __builtin_amdgcn_exp2f(fmaf(a2, bq.x, nm));
    p1 += __builtin_amdgcn_exp2f(fmaf(a2, bq.y, nm));
    p2 += __builtin_amdgcn_exp2f(fmaf(a2, bq.z, nm));
    p3 += __builtin_amdgcn_exp2f(fmaf(a2, bq.w, nm));
  }
  partial[w][lane] = (p0 + p1) + (p2 + p3);
  __syncthreads();

  if (w == 0) {
    const float part =
        (partial[0][lane] + partial[1][lane]) +
        (partial[2][lane] + partial[3][lane]);
    const float rp = 1.f / part;
    float ov[16];
#pragma unroll
    for (int t = 0; t < K; ++t) {
      const float sel = (a >= 0.f) ? seltop[t] : selbot[t];
      ov[t] = __builtin_amdgcn_exp2f(fmaf(a2, sel, nm)) * rp;
    }
    // row r -> 16 contiguous floats at (n, r/44, tp, (r%44)*16)
    float* op = out + (((size_t)(n * K + r / 44)) * T + tp) * HW + (r % 44) * K;
#pragma unroll
    for (int t4 = 0; t4 < 4; ++t4)
      ((float4*)op)[t4] = ((const float4*)ov)[t4];
  }
}

extern "C" void kernel_launch(void* const* d_in, const int* in_sizes, int n_in,
                              void* d_out, int out_size, void* d_ws, size_t ws_size,
                              hipStream_t stream) {
  (void)in_sizes; (void)n_in; (void)out_size; (void)ws_size;
  const float* x  = (const float*)d_in[0];
  const float* w1 = (const float*)d_in[1];
  const float* b1 = (const float*)d_in[2];
  const float* w2 = (const float*)d_in[3];
  const float* b2 = (const float*)d_in[4];
  // d_in[5] is top_k (=16), hardcoded as K.
  float* out = (float*)d_out;

  float* A    = (float*)d_ws;            // NS*HW
  float* B    = A + NS * HW;             // NS*HW
  float* btop = B + NS * HW;             // NS*K
  float* bbot = btop + NS * K;           // NS*K

  conv_select_kernel<<<NFR, 768, 0, stream>>>(x, w1, b1, w2, b2,
                                              A, B, btop, bbot);
  softmax_topk_kernel<<<NS * 11, 256, 0, stream>>>(A, B, btop, bbot, out);
}